// Round 1
// baseline (651.010 us; speedup 1.0000x reference)
//
#include <hip/hip_runtime.h>
#include <cmath>

#define NL 16
#define TABLE_SIZE (1u << 19)
#define TABLE_MASK (TABLE_SIZE - 1u)
#define P1 2654435761u
#define P2 805459861u

struct GridParams { float g[NL]; };

__global__ __launch_bounds__(256) void hash_embed_kernel(
    const float* __restrict__ xin,
    const float* __restrict__ tables,   // [16][524288][2] f32
    float* __restrict__ out,            // [N][32] f32
    int npts, GridParams gp)
{
  int n = blockIdx.x * blockDim.x + threadIdx.x;
  if (n >= npts) return;

  const float px = xin[3 * n + 0];
  const float py = xin[3 * n + 1];
  const float pz = xin[3 * n + 2];
  const float qx = fminf(fmaxf(px, -1.f), 1.f);
  const float qy = fminf(fmaxf(py, -1.f), 1.f);
  const float qz = fminf(fmaxf(pz, -1.f), 1.f);

  float2 acc[NL];

#pragma unroll
  for (int l = 0; l < NL; ++l) {
    const float g = gp.g[l];
    // bottom-left voxel index (as float then int) — matches floor((xc - BOX_MIN)/grid)
    const float fx = floorf((qx + 1.f) / g);
    const float fy = floorf((qy + 1.f) / g);
    const float fz = floorf((qz + 1.f) / g);
    // weights use the ORIGINAL (unclamped) x, vmin = bl*grid + BOX_MIN
    const float wx = (px - (fx * g - 1.f)) / g;
    const float wy = (py - (fy * g - 1.f)) / g;
    const float wz = (pz - (fz * g - 1.f)) / g;

    const unsigned hx0 = (unsigned)(int)fx;           // * PRIMES[0] == 1
    const unsigned hy0 = (unsigned)(int)fy * P1;
    const unsigned hz0 = (unsigned)(int)fz * P2;
    const unsigned hx1 = hx0 + 1u;
    const unsigned hy1 = hy0 + P1;
    const unsigned hz1 = hz0 + P2;

    const float2* __restrict__ tab = (const float2*)tables + (size_t)l * TABLE_SIZE;
    // corner order (i,j,k), i = x-offset outermost
    const float2 e000 = tab[(hx0 ^ hy0 ^ hz0) & TABLE_MASK];
    const float2 e001 = tab[(hx0 ^ hy0 ^ hz1) & TABLE_MASK];
    const float2 e010 = tab[(hx0 ^ hy1 ^ hz0) & TABLE_MASK];
    const float2 e011 = tab[(hx0 ^ hy1 ^ hz1) & TABLE_MASK];
    const float2 e100 = tab[(hx1 ^ hy0 ^ hz0) & TABLE_MASK];
    const float2 e101 = tab[(hx1 ^ hy0 ^ hz1) & TABLE_MASK];
    const float2 e110 = tab[(hx1 ^ hy1 ^ hz0) & TABLE_MASK];
    const float2 e111 = tab[(hx1 ^ hy1 ^ hz1) & TABLE_MASK];

    // lerp over x (i), then y (j), then z (k) — e0*(1-w) + e1*w, same as ref
    const float ux = 1.f - wx;
    const float a00x = e000.x * ux + e100.x * wx, a00y = e000.y * ux + e100.y * wx;
    const float a01x = e001.x * ux + e101.x * wx, a01y = e001.y * ux + e101.y * wx;
    const float a10x = e010.x * ux + e110.x * wx, a10y = e010.y * ux + e110.y * wx;
    const float a11x = e011.x * ux + e111.x * wx, a11y = e011.y * ux + e111.y * wx;

    const float uy = 1.f - wy;
    const float b0x = a00x * uy + a10x * wy, b0y = a00y * uy + a10y * wy;
    const float b1x = a01x * uy + a11x * wy, b1y = a01y * uy + a11y * wy;

    const float uz = 1.f - wz;
    acc[l].x = b0x * uz + b1x * wz;
    acc[l].y = b0y * uz + b1y * wz;
  }

  // coalesced-ish output: each thread writes its contiguous 128B row as 8x float4
  float4* o = (float4*)(out + (size_t)n * 32);
#pragma unroll
  for (int i = 0; i < 8; ++i)
    o[i] = make_float4(acc[2 * i].x, acc[2 * i].y, acc[2 * i + 1].x, acc[2 * i + 1].y);
}

extern "C" void kernel_launch(void* const* d_in, const int* in_sizes, int n_in,
                              void* d_out, int out_size, void* d_ws, size_t ws_size,
                              hipStream_t stream) {
  const float* x = (const float*)d_in[0];
  const float* tables = (const float*)d_in[1];
  float* out = (float*)d_out;
  const int npts = in_sizes[0] / 3;

  // Replicate the reference's f32 resolution computation on the host:
  // b = exp((ln 512 - ln 16)/15); res_l = floor(16 * b^l); grid = 2/res.
  GridParams gp;
  {
    const float b = expf((logf(512.0f) - logf(16.0f)) / 15.0f);
    for (int l = 0; l < NL; ++l) {
      const float r = floorf(16.0f * powf(b, (float)l));
      gp.g[l] = 2.0f / r;
    }
  }

  dim3 block(256);
  dim3 grid((npts + 255) / 256);
  hipLaunchKernelGGL(hash_embed_kernel, grid, block, 0, stream,
                     x, tables, out, npts, gp);
}